// Round 10
// baseline (97.048 us; speedup 1.0000x reference)
//
#include <hip/hip_runtime.h>

namespace {
constexpr int kH = 192, kW = 640, kHW = kH * kW;
constexpr int kW4g = kW / 4;            // 160 granules per row
constexpr int kHW4 = kHW / 4;           // granules per plane
constexpr int kB = 2, kC = 64;          // batch, image channels
constexpr int kN0 = 40000, kC0 = 32;    // level0 points/channels
constexpr int kN1 = 20000, kC1 = 64;    // level1 points/channels
constexpr int kCL = 67;                 // C1 + 3
constexpr int kBHW = kB * kHW;
constexpr int kWin4 = 2 * kBHW / 4;
// fused-tile geometry
constexpr int kTW = 32, kTH = 16;          // output tile
constexpr int kTilesX = kW / kTW;          // 20
constexpr int kTilesY = kH / kTH;          // 12
constexpr int kTiles = kB * kTilesX * kTilesY;  // 480
constexpr int kHaloW = kTW + 2, kHaloH = kTH + 2;  // 34 x 18
constexpr int kHaloN = kHaloW * kHaloH;    // 612
// k2 partition
constexpr int kScatB = 469;  // ceil(120000/256)

typedef float vf4 __attribute__((ext_vector_type(4)));

// ---------------------------------------------------------------------------
// init: fill the two winner maps with -1 (int4 stores).
// ---------------------------------------------------------------------------
__global__ __launch_bounds__(256) void kinit(int4* __restrict__ win4) {
  int i = blockIdx.x * 256 + threadIdx.x;
  if (i < kWin4) win4[i] = make_int4(-1, -1, -1, -1);
}

// ---------------------------------------------------------------------------
// K2: blocks [0,469): winner-index scatter (last-write-wins == max idx wins)
//     block 469: LDS-staged fold of the linear stages:
//       b' = W2@b0+b2; A1 = Wsp^T@W2 [9,67]; M0 = A1@W0 [9,35];
//       sb_k = Wsp[:,k].b'; wsum_k = sum_c Wsp[c,k]
// ---------------------------------------------------------------------------
__global__ __launch_bounds__(256) void k2(
    const float* __restrict__ coor0, const float* __restrict__ coor1,
    int* __restrict__ win0, int* __restrict__ win1,
    const float* __restrict__ W0, const float* __restrict__ b0,
    const float* __restrict__ W2, const float* __restrict__ b2,
    const float* __restrict__ Wsp, float* __restrict__ M0,
    float* __restrict__ A1g, float* __restrict__ sb,
    float* __restrict__ wsum) {
  __shared__ float W2s[kCL * kCL];
  __shared__ float W0s[kCL * 35];
  __shared__ float Wsps[kCL * 9];
  __shared__ float A1s[9 * kCL];
  __shared__ float bps[kCL];
  const int bid = blockIdx.x;
  if (bid < kScatB) {  // ---- scatter ----
    int idx = bid * 256 + threadIdx.x;
    const float* coor;
    int* win;
    int N;
    if (idx < kB * kN0) {
      coor = coor0; win = win0; N = kN0;
    } else {
      idx -= kB * kN0;
      if (idx >= kB * kN1) return;
      coor = coor1; win = win1; N = kN1;
    }
    int b = idx / N;
    float u = coor[(size_t)idx * 2 + 0];
    float v = coor[(size_t)idx * 2 + 1];
    u = fminf(fmaxf(u, 0.f), 1.f);
    v = fminf(fmaxf(v, 0.f), 1.f);
    int r = (int)(v * (float)kH);  // row from coor[:,1]
    int c = (int)(u * (float)kW);  // col from coor[:,0]
    if (r < kH && c < kW) {
      int n = idx - b * N;
      atomicMax(&win[b * kHW + r * kW + c], n);
    }
    return;
  }
  // ---- precomp (block 469, LDS-staged) ----
  const int t = threadIdx.x;
  for (int i = t; i < kCL * kCL; i += 256) W2s[i] = W2[i];
  for (int i = t; i < kCL * 35; i += 256) W0s[i] = W0[i];
  for (int i = t; i < kCL * 9; i += 256) Wsps[i] = Wsp[i];
  __syncthreads();
  if (t < kCL) {
    float s = b2[t];
    for (int j = 0; j < kCL; ++j) s += W2s[t * kCL + j] * b0[j];
    bps[t] = s;
  }
  for (int idx = t; idx < 9 * kCL; idx += 256) {
    int k = idx / kCL, j = idx - k * kCL;
    float s = 0.f;
    for (int c = 0; c < kCL; ++c) s += Wsps[c * 9 + k] * W2s[c * kCL + j];
    A1s[idx] = s;
    A1g[idx] = s;
  }
  __syncthreads();
  for (int idx = t; idx < 9 * 35; idx += 256) {
    int k = idx / 35, i = idx - k * 35;
    float s = 0.f;
    for (int j = 0; j < kCL; ++j) s += A1s[k * kCL + j] * W0s[j * 35 + i];
    M0[idx] = s;
  }
  if (t < 9) {
    float s = 0.f;
    for (int c = 0; c < kCL; ++c) s += Wsps[c * 9 + t] * bps[c];
    sb[t] = s;
  } else if (t >= 16 && t < 25) {
    int k = t - 16;
    float s = 0.f;
    for (int c = 0; c < kCL; ++c) s += Wsps[c * 9 + k];
    wsum[k] = s;
  }
}

// ---------------------------------------------------------------------------
// kfuse: one 32x16 output tile per block (480 blocks, 256 threads).
// phase 1 (34x18 halo region, ~2.4 px/thread):
//   gv   = b3 + W3 . x[:,px]        (x tile+halo -> L2-warm for phase 2)
//   y[k] = wsum[k]*gv + sb[k] + [w0>=0] M0[k].p0 + [w1>=0] A1[k].p1
//   -> ylds[9][18][34]  (out-of-image px -> 0 == padded-plane semantics)
// phase 2 (128 granules x 2 channel-chunks):
//   logit = bsp + sum_{r,d} ylds[3r+d][lh+r][lw+d]; att = sigmoid(logit)
//   out[c,px] = x[c,px] * att       (x loads L2-hit, NT stores)
// ---------------------------------------------------------------------------
__global__ __launch_bounds__(256) void kfuse(
    const float* __restrict__ x_rgb, const int* __restrict__ win0,
    const int* __restrict__ win1, const float* __restrict__ feat0,
    const float* __restrict__ vox0, const float* __restrict__ feat1,
    const float* __restrict__ vox1, const float* __restrict__ M0,
    const float* __restrict__ A1, const float* __restrict__ sb,
    const float* __restrict__ wsum, const float* __restrict__ W3,
    const float* __restrict__ b3, const float* __restrict__ bsp,
    float* __restrict__ out) {
  __shared__ float ylds[9][kHaloH][kHaloW];  // 22.0 KB
  const int t = threadIdx.x;
  const int tile = blockIdx.x;
  const int b = tile / (kTilesX * kTilesY);
  const int tr = tile - b * (kTilesX * kTilesY);
  const int ty = tr / kTilesX, tx = tr - ty * kTilesX;
  const int h0 = ty * kTH, w0 = tx * kTW;
  const float* xb = x_rgb + (size_t)b * kC * kHW;

  // ---- phase 1 ----
  for (int i = t; i < kHaloN; i += 256) {
    const int hh = i / kHaloW, ww = i - hh * kHaloW;
    const int h = h0 + hh - 1, w = w0 + ww - 1;
    float y[9];
    if (h < 0 || h >= kH || w < 0 || w >= kW) {
#pragma unroll
      for (int k = 0; k < 9; ++k) y[k] = 0.f;
    } else {
      const int p = h * kW + w;
      float gv = b3[0];
#pragma unroll 16
      for (int c = 0; c < kC; ++c) gv += W3[c] * xb[(size_t)c * kHW + p];
#pragma unroll
      for (int k = 0; k < 9; ++k) y[k] = wsum[k] * gv + sb[k];
      const int pix = b * kHW + p;
      const int w0i = win0[pix];
      if (w0i >= 0) {
        const float4* f0 =
            (const float4*)(feat0 + ((size_t)b * kN0 + w0i) * kC0);
#pragma unroll
        for (int i4 = 0; i4 < 8; ++i4) {
          float4 v = f0[i4];
#pragma unroll
          for (int k = 0; k < 9; ++k) {
            const float* m = M0 + k * 35 + i4 * 4;
            y[k] += m[0] * v.x + m[1] * v.y + m[2] * v.z + m[3] * v.w;
          }
        }
        const float* v0 = vox0 + ((size_t)b * kN0 + w0i) * 3;
#pragma unroll
        for (int ii = 0; ii < 3; ++ii) {
          float v = v0[ii];
#pragma unroll
          for (int k = 0; k < 9; ++k) y[k] += M0[k * 35 + kC0 + ii] * v;
        }
      }
      const int w1i = win1[pix];
      if (w1i >= 0) {
        const float4* f1 =
            (const float4*)(feat1 + ((size_t)b * kN1 + w1i) * kC1);
#pragma unroll
        for (int i4 = 0; i4 < 16; ++i4) {
          float4 v = f1[i4];
#pragma unroll
          for (int k = 0; k < 9; ++k) {
            const float* m = A1 + k * kCL + i4 * 4;
            y[k] += m[0] * v.x + m[1] * v.y + m[2] * v.z + m[3] * v.w;
          }
        }
        const float* v1 = vox1 + ((size_t)b * kN1 + w1i) * 3;
#pragma unroll
        for (int ii = 0; ii < 3; ++ii) {
          float v = v1[ii];
#pragma unroll
          for (int k = 0; k < 9; ++k) y[k] += A1[k * kCL + kC1 + ii] * v;
        }
      }
    }
#pragma unroll
    for (int k = 0; k < 9; ++k) ylds[k][hh][ww] = y[k];
  }
  __syncthreads();

  // ---- phase 2 ----
  const int g = t & 127, q = t >> 7;   // granule, channel half
  const int lh = g >> 3, w4 = g & 7;   // tile row, granule-in-row
  const float bias = bsp[0];
  float4 lg = make_float4(bias, bias, bias, bias);
#pragma unroll
  for (int r = 0; r < 3; ++r) {
#pragma unroll
    for (int d = 0; d < 3; ++d) {
      const float* yrow = &ylds[3 * r + d][lh + r][w4 * 4 + d];
      lg.x += yrow[0];
      lg.y += yrow[1];
      lg.z += yrow[2];
      lg.w += yrow[3];
    }
  }
  float4 att;
  att.x = 1.f / (1.f + __expf(-lg.x));
  att.y = 1.f / (1.f + __expf(-lg.y));
  att.z = 1.f / (1.f + __expf(-lg.z));
  att.w = 1.f / (1.f + __expf(-lg.w));

  const int p4g = (h0 + lh) * kW4g + tx * 8 + w4;  // global granule index
  const float4* xr = (const float4*)xb + p4g;
  vf4* op = (vf4*)(out + (size_t)b * kC * kHW) + p4g;
#pragma unroll
  for (int cc = 0; cc < 32; ++cc) {
    const int c = q * 32 + cc;
    float4 x4 = xr[(size_t)c * kHW4];
    vf4 r4;
    r4.x = x4.x * att.x;
    r4.y = x4.y * att.y;
    r4.z = x4.z * att.z;
    r4.w = x4.w * att.w;
    __builtin_nontemporal_store(r4, op + (size_t)c * kHW4);
  }
}

}  // namespace

extern "C" void kernel_launch(void* const* d_in, const int* in_sizes, int n_in,
                              void* d_out, int out_size, void* d_ws,
                              size_t ws_size, hipStream_t stream) {
  const float* x_rgb = (const float*)d_in[0];
  const float* feat0 = (const float*)d_in[1];
  const float* coor0 = (const float*)d_in[2];
  const float* vox0 = (const float*)d_in[3];
  const float* feat1 = (const float*)d_in[4];
  const float* coor1 = (const float*)d_in[5];
  const float* vox1 = (const float*)d_in[6];
  const float* W0 = (const float*)d_in[7];
  const float* b0 = (const float*)d_in[8];
  const float* W2 = (const float*)d_in[9];
  const float* b2 = (const float*)d_in[10];
  const float* W3 = (const float*)d_in[11];
  const float* b3 = (const float*)d_in[12];
  const float* Wsp = (const float*)d_in[13];
  const float* bsp = (const float*)d_in[14];
  float* out = (float*)d_out;

  // workspace: win0[BHW] | win1[BHW] | M0[9*35] | A1[9*67] | sb[9] | wsum[9]
  int* win0 = (int*)d_ws;
  int* win1 = win0 + (size_t)kBHW;
  float* M0 = (float*)(win1 + (size_t)kBHW);
  float* A1 = M0 + 9 * 35;
  float* sb = A1 + 9 * kCL;
  float* wsum = sb + 9;

  kinit<<<(kWin4 + 255) / 256, 256, 0, stream>>>((int4*)win0);
  k2<<<kScatB + 1, 256, 0, stream>>>(coor0, coor1, win0, win1, W0, b0, W2, b2,
                                     Wsp, M0, A1, sb, wsum);
  kfuse<<<kTiles, 256, 0, stream>>>(x_rgb, win0, win1, feat0, vox0, feat1,
                                    vox1, M0, A1, sb, wsum, W3, b3, bsp, out);
}

// Round 11
// 70.348 us; speedup vs baseline: 1.3795x; 1.3795x over previous
//
#include <hip/hip_runtime.h>

namespace {
constexpr int kH = 192, kW = 640, kHW = kH * kW;
constexpr int kW4g = kW / 4;            // 160 granules per row
constexpr int kHW4 = kHW / 4;           // 30720 granules per plane
constexpr int kB = 2, kC = 64;          // batch, image channels
constexpr int kN0 = 40000, kC0 = 32;    // level0 points/channels
constexpr int kN1 = 20000, kC1 = 64;    // level1 points/channels
constexpr int kCL = 67;                 // C1 + 3
constexpr int kBHW = kB * kHW;
// zero-padded y planes: 18 = 9 taps x B, rows H+2, pitch W+8 (interior at +1,+4)
constexpr int kPH = kH + 2, kPW = kW + 8;  // 194 x 648
constexpr int kPW4 = kPW / 4;              // 162
constexpr int kPlane = kPH * kPW;          // 125712
constexpr int kYPF = 18 * kPlane;
constexpr int kWin4 = 2 * kBHW / 4;
// border float4s per plane: row0 (162) + row193 (162) + 192 rows x {col0,col161}
constexpr int kBord = 162 + 162 + 192 * 2;  // 708
constexpr int kBordTot = 18 * kBord;        // 12744
// K2 block partition
constexpr int kScatB = 469;   // ceil(120000/256) scatter blocks
constexpr int kGateB0 = 470;  // gate blocks start (469 = precomp)
constexpr int kGateB = kB * kHW4 * 4 / 256;  // 960
// kpass2 partition: 240 granule-chunks x 2 channel-halves
constexpr int kChunks = kB * kHW4 / 256;  // 240

typedef float vf4 __attribute__((ext_vector_type(4)));

// ---------------------------------------------------------------------------
// init: zero ONLY the padded-y borders (interior is fully rewritten by kgy
// each replay) and fill the two winner maps with -1.
// ---------------------------------------------------------------------------
__global__ __launch_bounds__(256) void kinit(float* __restrict__ yp,
                                             int4* __restrict__ win4) {
  int i = blockIdx.x * 256 + threadIdx.x;
  if (i < kBordTot) {
    int plane = i / kBord, r = i - plane * kBord;
    float4* base = (float4*)(yp + (size_t)plane * kPlane);
    int f4;
    if (r < 162) {
      f4 = r;                                  // row 0
    } else if (r < 324) {
      f4 = 193 * kPW4 + (r - 162);             // row 193
    } else {
      int rr = r - 324;
      int row = 1 + (rr >> 1);
      f4 = row * kPW4 + ((rr & 1) ? (kPW4 - 1) : 0);  // cols 0-3 / 644-647
    }
    base[f4] = make_float4(0.f, 0.f, 0.f, 0.f);
  } else {
    int j = i - kBordTot;
    if (j < kWin4) win4[j] = make_int4(-1, -1, -1, -1);
  }
}

// ---------------------------------------------------------------------------
// K2 (heterogeneous, all parts independent given win init):
//   blocks [0,469): winner-index scatter (last-write-wins == max index wins)
//   block  469    : LDS-staged fold of linear stages ->
//        b' = W2@b0+b2; A1 = Wsp^T@W2 [9,67]; M0 = A1@W0 [9,35];
//        sb_k = Wsp[:,k].b'; wsum_k = sum_c Wsp[c,k]
//   blocks [470,1430): gate partials
//        gpart[q][pix] = sum_{c in 16-chunk q} W3[c]*x_rgb[b,c,pix]
// ---------------------------------------------------------------------------
__global__ __launch_bounds__(256) void k2(
    const float* __restrict__ coor0, const float* __restrict__ coor1,
    int* __restrict__ win0, int* __restrict__ win1,
    const float* __restrict__ W0, const float* __restrict__ b0,
    const float* __restrict__ W2, const float* __restrict__ b2,
    const float* __restrict__ Wsp, float* __restrict__ M0,
    float* __restrict__ A1g, float* __restrict__ sb, float* __restrict__ wsum,
    const float* __restrict__ x_rgb, const float* __restrict__ W3,
    float* __restrict__ gpart) {
  __shared__ float W2s[kCL * kCL];
  __shared__ float W0s[kCL * 35];
  __shared__ float Wsps[kCL * 9];
  __shared__ float A1s[9 * kCL];
  __shared__ float bps[kCL];
  const int bid = blockIdx.x;
  if (bid >= kGateB0) {  // ---- gate ----
    const int j = (bid - kGateB0) * 256 + threadIdx.x;
    const int T = kB * kHW4;           // 61440 granules
    const int q = j / T;               // channel chunk 0..3 (uniform/block)
    const int gran = j - q * T;
    const int b = gran / kHW4;
    const int p4 = gran - b * kHW4;
    const float4* xr = (const float4*)(x_rgb + (size_t)b * kC * kHW) + p4;
    float4 acc = make_float4(0.f, 0.f, 0.f, 0.f);
#pragma unroll
    for (int cc = 0; cc < 16; ++cc) {
      const int c = q * 16 + cc;
      float wv = W3[c];
      float4 x4 = xr[(size_t)c * kHW4];
      acc.x += wv * x4.x;
      acc.y += wv * x4.y;
      acc.z += wv * x4.z;
      acc.w += wv * x4.w;
    }
    ((float4*)gpart)[j] = acc;
    return;
  }
  if (bid < kScatB) {  // ---- scatter ----
    int idx = bid * 256 + threadIdx.x;
    const float* coor;
    int* win;
    int N;
    if (idx < kB * kN0) {
      coor = coor0; win = win0; N = kN0;
    } else {
      idx -= kB * kN0;
      if (idx >= kB * kN1) return;
      coor = coor1; win = win1; N = kN1;
    }
    int b = idx / N;
    float u = coor[(size_t)idx * 2 + 0];
    float v = coor[(size_t)idx * 2 + 1];
    u = fminf(fmaxf(u, 0.f), 1.f);
    v = fminf(fmaxf(v, 0.f), 1.f);
    int r = (int)(v * (float)kH);  // row from coor[:,1]
    int c = (int)(u * (float)kW);  // col from coor[:,0]
    if (r < kH && c < kW) {
      int n = idx - b * N;
      atomicMax(&win[b * kHW + r * kW + c], n);
    }
    return;
  }
  // ---- precomp (block 469, LDS-staged) ----
  const int t = threadIdx.x;
  for (int i = t; i < kCL * kCL; i += 256) W2s[i] = W2[i];
  for (int i = t; i < kCL * 35; i += 256) W0s[i] = W0[i];
  for (int i = t; i < kCL * 9; i += 256) Wsps[i] = Wsp[i];
  __syncthreads();
  if (t < kCL) {
    float s = b2[t];
    for (int j = 0; j < kCL; ++j) s += W2s[t * kCL + j] * b0[j];
    bps[t] = s;
  }
  for (int idx = t; idx < 9 * kCL; idx += 256) {
    int k = idx / kCL, j = idx - k * kCL;
    float s = 0.f;
    for (int c = 0; c < kCL; ++c) s += Wsps[c * 9 + k] * W2s[c * kCL + j];
    A1s[idx] = s;
    A1g[idx] = s;
  }
  __syncthreads();
  for (int idx = t; idx < 9 * 35; idx += 256) {
    int k = idx / 35, i = idx - k * 35;
    float s = 0.f;
    for (int j = 0; j < kCL; ++j) s += A1s[k * kCL + j] * W0s[j * 35 + i];
    M0[idx] = s;
  }
  if (t < 9) {
    float s = 0.f;
    for (int c = 0; c < kCL; ++c) s += Wsps[c * 9 + t] * bps[c];
    sb[t] = s;
  } else if (t >= 16 && t < 25) {
    int k = t - 16;
    float s = 0.f;
    for (int c = 0; c < kCL; ++c) s += Wsps[c * 9 + k];
    wsum[k] = s;
  }
}

// ---------------------------------------------------------------------------
// per-SOURCE-pixel tap projection, 3-way tap-split for occupancy:
// block handles 256 pixels x 3 taps (tg = stencil row). Gathers repeat 3x
// (L2/L3-served; adjacent blocks share the pixel range for locality).
// ---------------------------------------------------------------------------
__global__ __launch_bounds__(256) void kgy(
    const float* __restrict__ gpart, const int* __restrict__ win0,
    const int* __restrict__ win1, const float* __restrict__ feat0,
    const float* __restrict__ vox0, const float* __restrict__ feat1,
    const float* __restrict__ vox1, const float* __restrict__ M0,
    const float* __restrict__ A1, const float* __restrict__ sb,
    const float* __restrict__ wsum, const float* __restrict__ b3,
    float* __restrict__ yp) {
  const int blk = blockIdx.x;
  const int tg = blk % 3;              // tap row group: taps 3tg..3tg+2
  const int pix = (blk / 3) * 256 + threadIdx.x;
  const int b = pix / kHW;
  const int pp = pix - b * kHW;
  const int h = pp / kW;
  const int w = pp - h * kW;
  const float gv = b3[0] + gpart[pix] + gpart[kBHW + pix] +
                   gpart[2 * kBHW + pix] + gpart[3 * kBHW + pix];
  float y[3];
#pragma unroll
  for (int kk = 0; kk < 3; ++kk)
    y[kk] = wsum[3 * tg + kk] * gv + sb[3 * tg + kk];

  const int w0 = win0[pix];
  if (w0 >= 0) {
    const float4* f0 = (const float4*)(feat0 + ((size_t)b * kN0 + w0) * kC0);
#pragma unroll
    for (int i4 = 0; i4 < 8; ++i4) {
      float4 v = f0[i4];
#pragma unroll
      for (int kk = 0; kk < 3; ++kk) {
        const float* m = M0 + (3 * tg + kk) * 35 + i4 * 4;
        y[kk] += m[0] * v.x + m[1] * v.y + m[2] * v.z + m[3] * v.w;
      }
    }
    const float* v0 = vox0 + ((size_t)b * kN0 + w0) * 3;
#pragma unroll
    for (int i = 0; i < 3; ++i) {
      float v = v0[i];
#pragma unroll
      for (int kk = 0; kk < 3; ++kk)
        y[kk] += M0[(3 * tg + kk) * 35 + kC0 + i] * v;
    }
  }
  const int w1 = win1[pix];
  if (w1 >= 0) {
    const float4* f1 = (const float4*)(feat1 + ((size_t)b * kN1 + w1) * kC1);
#pragma unroll
    for (int i4 = 0; i4 < 16; ++i4) {
      float4 v = f1[i4];
#pragma unroll
      for (int kk = 0; kk < 3; ++kk) {
        const float* m = A1 + (3 * tg + kk) * kCL + i4 * 4;
        y[kk] += m[0] * v.x + m[1] * v.y + m[2] * v.z + m[3] * v.w;
      }
    }
    const float* v1 = vox1 + ((size_t)b * kN1 + w1) * 3;
#pragma unroll
    for (int i = 0; i < 3; ++i) {
      float v = v1[i];
#pragma unroll
      for (int kk = 0; kk < 3; ++kk)
        y[kk] += A1[(3 * tg + kk) * kCL + kC1 + i] * v;
    }
  }
#pragma unroll
  for (int kk = 0; kk < 3; ++kk) {
    yp[((size_t)((3 * tg + kk) * kB + b) * kPH + (h + 1)) * kPW + 4 + w] =
        y[kk];
  }
}

// ---------------------------------------------------------------------------
// fused stencil+sigmoid+multiply, att-in-register:
// block <-> (256-granule chunk, channel HALF). thread <-> granule.
// stencil+sigmoid computed ONCE per thread (att in registers; 2x total
// instead of 4x), then a 32-iteration channel loop of perfectly coalesced
// NT float4 loads/stores.
// ---------------------------------------------------------------------------
__global__ __launch_bounds__(256) void kpass2(const float* __restrict__ x_rgb,
                                              const float* __restrict__ yp,
                                              const float* __restrict__ bsp,
                                              float* __restrict__ out) {
  const int bid = blockIdx.x;
  const int q = bid / kChunks;         // channel half 0..1 (uniform/block)
  const int chunk = bid - q * kChunks;
  const int gran = chunk * 256 + threadIdx.x;
  const int b = gran / kHW4;
  const int p4 = gran - b * kHW4;
  const int h = p4 / kW4g;
  const int w4 = p4 - h * kW4g;

  const float bias = bsp[0];
  float4 lg = make_float4(bias, bias, bias, bias);
#pragma unroll
  for (int r = 0; r < 3; ++r) {
    const size_t rowoff = ((size_t)h + r) * kPW + 4 * w4;
    const float* pA = yp + (size_t)((3 * r + 0) * kB + b) * kPlane + rowoff;
    const float* pB = yp + (size_t)((3 * r + 1) * kB + b) * kPlane + rowoff;
    const float* pC = yp + (size_t)((3 * r + 2) * kB + b) * kPlane + rowoff;
    float LA = pA[3];
    float4 a4 = *(const float4*)(pA + 4);
    float4 b4 = *(const float4*)(pB + 4);
    float4 c4 = *(const float4*)(pC + 4);
    float RC = pC[8];
    lg.x += LA + b4.x + c4.y;
    lg.y += a4.x + b4.y + c4.z;
    lg.z += a4.y + b4.z + c4.w;
    lg.w += a4.z + b4.w + RC;
  }
  float4 att;
  att.x = 1.f / (1.f + __expf(-lg.x));
  att.y = 1.f / (1.f + __expf(-lg.y));
  att.z = 1.f / (1.f + __expf(-lg.z));
  att.w = 1.f / (1.f + __expf(-lg.w));

  const vf4* xr = (const vf4*)(x_rgb + (size_t)b * kC * kHW) + p4;
  vf4* op = (vf4*)(out + (size_t)b * kC * kHW) + p4;
#pragma unroll
  for (int cc = 0; cc < 32; ++cc) {
    const int c = q * 32 + cc;
    vf4 x4 = __builtin_nontemporal_load(xr + (size_t)c * kHW4);
    vf4 r4;
    r4.x = x4.x * att.x;
    r4.y = x4.y * att.y;
    r4.z = x4.z * att.z;
    r4.w = x4.w * att.w;
    __builtin_nontemporal_store(r4, op + (size_t)c * kHW4);
  }
}

}  // namespace

extern "C" void kernel_launch(void* const* d_in, const int* in_sizes, int n_in,
                              void* d_out, int out_size, void* d_ws,
                              size_t ws_size, hipStream_t stream) {
  const float* x_rgb = (const float*)d_in[0];
  const float* feat0 = (const float*)d_in[1];
  const float* coor0 = (const float*)d_in[2];
  const float* vox0 = (const float*)d_in[3];
  const float* feat1 = (const float*)d_in[4];
  const float* coor1 = (const float*)d_in[5];
  const float* vox1 = (const float*)d_in[6];
  const float* W0 = (const float*)d_in[7];
  const float* b0 = (const float*)d_in[8];
  const float* W2 = (const float*)d_in[9];
  const float* b2 = (const float*)d_in[10];
  const float* W3 = (const float*)d_in[11];
  const float* b3 = (const float*)d_in[12];
  const float* Wsp = (const float*)d_in[13];
  const float* bsp = (const float*)d_in[14];
  float* out = (float*)d_out;

  // workspace: yp[18*194*648] | gpart[4*BHW] | win0[BHW] | win1[BHW] | mats
  float* yp = (float*)d_ws;
  float* gpart = yp + (size_t)kYPF;
  int* win0 = (int*)(gpart + (size_t)4 * kBHW);
  int* win1 = win0 + (size_t)kBHW;
  float* M0 = (float*)(win1 + (size_t)kBHW);
  float* A1 = M0 + 9 * 35;
  float* sb = A1 + 9 * kCL;
  float* wsum = sb + 9;

  const int ninit = kBordTot + kWin4;
  kinit<<<(ninit + 255) / 256, 256, 0, stream>>>(yp, (int4*)win0);
  k2<<<kGateB0 + kGateB, 256, 0, stream>>>(coor0, coor1, win0, win1, W0, b0,
                                           W2, b2, Wsp, M0, A1, sb, wsum,
                                           x_rgb, W3, gpart);
  kgy<<<3 * kBHW / 256, 256, 0, stream>>>(gpart, win0, win1, feat0, vox0,
                                          feat1, vox1, M0, A1, sb, wsum, b3,
                                          yp);
  kpass2<<<2 * kChunks, 256, 0, stream>>>(x_rgb, yp, bsp, out);
}